// Round 5
// baseline (435.146 us; speedup 1.0000x reference)
//
#include <hip/hip_runtime.h>
#include <cstdint>

#define I_NODES 32767
#define N_NODES 65535
#define NLEAF   32768
#define NT      32768          // node columns for channel-major activations
#define CSTRIDE 65536          // node columns for c_T
#define PREP_BLOCKS 4002

typedef float f32x4 __attribute__((ext_vector_type(4)));
typedef short bf16x8 __attribute__((ext_vector_type(8)));
typedef int   i32x4 __attribute__((ext_vector_type(4)));
typedef int   i32x2 __attribute__((ext_vector_type(2)));

__device__ __forceinline__ float sigmoidf_(float v) {
    return 1.0f / (1.0f + __expf(-v));
}
__device__ __forceinline__ float tanhf_(float v) {
    return 1.0f - 2.0f / (1.0f + __expf(2.0f * v));
}
__device__ __forceinline__ short f2bf(float f) {
    union { float f; unsigned u; } v; v.f = f;
    unsigned r = (v.u + 0x7FFF + ((v.u >> 16) & 1)) >> 16;
    return (short)r;
}
__device__ __forceinline__ float bf2f(short b) {
    union { float f; unsigned u; } v; v.u = ((unsigned)(unsigned short)b) << 16;
    return v.f;
}

// ---------------------------------------------------------------------------
// prep_all: weight transposes->bf16 (wT[outch][inch]) + packed encoder
// weights + biases + feature pack (node-major, 8-wide vector stores) +
// leaf-output constant.
// Blocks >= PREP_BLOCKS: LDS-tiled transpose c_a leaves -> cafT bf16.
// ---------------------------------------------------------------------------
__global__ __launch_bounds__(256) void prep_all(
    const float* __restrict__ w_xou, const float* __restrict__ w_btoa,
    const float* __restrict__ w_ca,  const float* __restrict__ w_cb,
    const float* __restrict__ w_ab,  const float* __restrict__ w_o1,
    const float* __restrict__ w_op1, const float* __restrict__ w_tb1,
    const float* __restrict__ w_ft1, const float* __restrict__ w_jn1,
    const float* __restrict__ w_op2, const float* __restrict__ w_tb2,
    const float* __restrict__ w_ft2, const float* __restrict__ w_jn2,
    const float* __restrict__ b_op1, const float* __restrict__ b_tb1,
    const float* __restrict__ b_ft1, const float* __restrict__ b_jn1,
    const float* __restrict__ b_op2, const float* __restrict__ b_tb2,
    const float* __restrict__ b_ft2, const float* __restrict__ b_jn2,
    const float* __restrict__ oper,  const float* __restrict__ tbf,
    const float* __restrict__ ftf,   const float* __restrict__ jnf,
    const float* __restrict__ b_o1,  const float* __restrict__ w_o2,
    const float* __restrict__ b_o2,  const float* __restrict__ caf,
    short* __restrict__ wT_xou, short* __restrict__ wT_btoa,
    short* __restrict__ wT_ca,  short* __restrict__ wT_cb,
    short* __restrict__ wT_ab,  short* __restrict__ wT_o1,
    short* __restrict__ W1T,    short* __restrict__ W2T,
    float* __restrict__ b1cat,  float* __restrict__ b2cat,
    short* __restrict__ xfeat,  float* __restrict__ outv,
    short* __restrict__ cafT)
{
    if (blockIdx.x >= PREP_BLOCKS) {
        // transpose section: [32768 x 256] f32 -> [256 x 32768] bf16
        __shared__ float tile[64][65];
        const int bid = blockIdx.x - PREP_BLOCKS;
        const int t = threadIdx.x;
        const int r0 = (bid & 511) * 64;   // leaf rows
        const int c0 = (bid >> 9) * 64;    // channels
        const int lane = t & 63, seg = t >> 6;
#pragma unroll
        for (int i = 0; i < 16; i++) {
            int rr = seg + i * 4;
            tile[rr][lane] = caf[(size_t)(r0 + rr) * 256 + c0 + lane];
        }
        __syncthreads();
#pragma unroll
        for (int i = 0; i < 16; i++) {
            int cc = seg + i * 4;
            cafT[(size_t)(c0 + cc) * NT + r0 + lane] = f2bf(tile[lane][cc]);
        }
        return;
    }
    int r = blockIdx.x * 256 + threadIdx.x;
    if (r < 196608) { wT_xou[r] = f2bf(w_xou[(size_t)(r % 256) * 768 + r / 256]); return; }
    r -= 196608;
    if (r < 81920)  { wT_btoa[r] = f2bf(w_btoa[(size_t)(r % 320) * 256 + r / 320]); return; }
    r -= 81920;
    if (r < 65536)  { wT_ca[r] = f2bf(w_ca[(size_t)(r % 256) * 256 + r / 256]); return; }
    r -= 65536;
    if (r < 65536)  { wT_cb[r] = f2bf(w_cb[(size_t)(r % 256) * 256 + r / 256]); return; }
    r -= 65536;
    if (r < 65536)  { wT_ab[r] = f2bf(w_ab[(size_t)(r % 256) * 256 + r / 256]); return; }
    r -= 65536;
    if (r < 32768)  { wT_o1[r] = f2bf(w_o1[(size_t)(r % 256) * 128 + r / 256]); return; }
    r -= 32768;
    if (r < 24576) {
        int j = r / 96, k = r % 96;
        int s = j >> 6, jj = j & 63;
        int off = (s == 0) ? 0 : (s == 1) ? 4 : (s == 2) ? 15 : 33;
        int Ks  = (s == 0) ? 4 : (s == 1) ? 11 : (s == 2) ? 18 : 37;
        const float* w = (s == 0) ? w_op1 : (s == 1) ? w_tb1 : (s == 2) ? w_ft1 : w_jn1;
        W1T[r] = (k >= off && k < off + Ks) ? f2bf(w[(k - off) * 64 + jj]) : (short)0;
        return;
    }
    r -= 24576;
    if (r < 65536) {
        int j = r >> 8, k = r & 255;
        int s = j >> 6, jj = j & 63;
        const float* w = (s == 0) ? w_op2 : (s == 1) ? w_tb2 : (s == 2) ? w_ft2 : w_jn2;
        W2T[r] = ((k >> 6) == s) ? f2bf(w[(k & 63) * 64 + jj]) : (short)0;
        return;
    }
    r -= 65536;
    if (r < 256) {
        int s = r >> 6, jj = r & 63;
        b1cat[r] = (s == 0) ? b_op1[jj] : (s == 1) ? b_tb1[jj] : (s == 2) ? b_ft1[jj] : b_jn1[jj];
        return;
    }
    r -= 256;
    if (r < 256) {
        int s = r >> 6, jj = r & 63;
        b2cat[r] = (s == 0) ? b_op2[jj] : (s == 1) ? b_tb2[jj] : (s == 2) ? b_ft2[jj] : b_jn2[jj];
        return;
    }
    r -= 256;
    if (r < 393216) {
        // xfeat pack, 8 features per thread, one short8 store (G13)
        int node = r / 12, fb = (r % 12) * 8;
        short v8[8];
        if (node < I_NODES) {
#pragma unroll
            for (int i = 0; i < 8; i++) {
                int f = fb + i;
                float v = 0.0f;
                if (f < 4)       v = oper[node * 4 + f];
                else if (f < 15) v = tbf[node * 11 + (f - 4)];
                else if (f < 33) v = ftf[node * 18 + (f - 15)];
                else if (f < 70) v = jnf[node * 37 + (f - 33)];
                v8[i] = f2bf(v);
            }
        } else {
#pragma unroll
            for (int i = 0; i < 8; i++) v8[i] = 0;
        }
        *(bf16x8*)&xfeat[node * 96 + fb] = *(bf16x8*)v8;
        return;
    }
    r -= 393216;
    if (r < 32768) {
        // leaf output: h=0 -> hid = relu(b_o1), out = sigmoid(b_o2 + hid.w_o2)
        float s = 0.0f;
        for (int k = 0; k < 128; k++) s += fmaxf(b_o1[k], 0.0f) * w_o2[k];
        outv[I_NODES + r] = sigmoidf_(s + b_o2[0]);
    }
}

// ---------------------------------------------------------------------------
// Transposed-world MFMA GEMM: out_T[ch][node] = act( A_w[M x K] @ B + bias ).
// A_w = transposed weight, bf16 row-major [M][K]. Grid (M/128, 256).
// BLAYOUT 0: B node-major [32768 x K] (BSRC 0 bf16 / 1 fp32-convert).
// BLAYOUT 1: B channel-major bf16 [K x BN] (BSRC must be 0).
// MODE 0: fp32 fout[row*ON + COLOFF + col] with ACT.
// MODE 2: bf16 bout[row*ON + col] with ACT.
// MODE 3: t-fusion: bout = e1*caf + sigmoid(v)*e2 (all channel-major bf16).
// MODE 4: head fusion (M=128): out[col] = sigmoid(b_o2 + sum_row relu(v)*w_o2[row]).
// ---------------------------------------------------------------------------
template <int ACT, int MODE, int BSRC, int BLAYOUT>
__device__ __forceinline__ void gemm_body(
    short* Asl, short* Bsl,
    const short* __restrict__ A, const void* __restrict__ Braw,
    const float* __restrict__ bias,
    float* __restrict__ fout, float* __restrict__ fout1, float* __restrict__ fout2,
    short* __restrict__ bout,
    const short* __restrict__ caf, const short* __restrict__ e1,
    const short* __restrict__ e2,
    const float* __restrict__ w_o2, const float* __restrict__ b_o2,
    float* __restrict__ outv,
    int K, int BN, int ON, int COLOFF)
{
    const int tid = threadIdx.x;
    const int bm = blockIdx.x * 128;
    const int bn = blockIdx.y * 128;
    const int wave = tid >> 6, lane = tid & 63;
    const int m = lane & 15, q = lane >> 4;
    const int rw = (wave & 1) * 64, cw = (wave >> 1) * 64;

    f32x4 acc[4][4] = {};

    for (int k0 = 0; k0 < K; k0 += 32) {
        // A staging: [128 rows][32 k] from bf16 row-major
#pragma unroll
        for (int i = 0; i < 2; i++) {
            int id = tid + i * 256;
            int row = id >> 2, ch = id & 3;
            i32x4 va = *(const i32x4*)(A + (size_t)(bm + row) * K + k0 + ch * 8);
            *(i32x4*)&Asl[row * 40 + ch * 8] = va;
        }
        // B staging -> Bsl[n][k] (pitch 40)
        if (BLAYOUT == 0) {
#pragma unroll
            for (int i = 0; i < 2; i++) {
                int id = tid + i * 256;
                int row = id >> 2, ch = id & 3;
                if (BSRC == 0) {
                    const short* Bs = (const short*)Braw;
                    i32x4 vb = *(const i32x4*)(Bs + (size_t)(bn + row) * K + k0 + ch * 8);
                    *(i32x4*)&Bsl[row * 40 + ch * 8] = vb;
                } else {
                    const float* Bf = (const float*)Braw;
                    const float* src = Bf + (size_t)(bn + row) * K + k0 + ch * 8;
                    f32x4 a0 = *(const f32x4*)src;
                    f32x4 a1 = *(const f32x4*)(src + 4);
                    bf16x8 tv;
                    tv[0] = f2bf(a0[0]); tv[1] = f2bf(a0[1]); tv[2] = f2bf(a0[2]); tv[3] = f2bf(a0[3]);
                    tv[4] = f2bf(a1[0]); tv[5] = f2bf(a1[1]); tv[6] = f2bf(a1[2]); tv[7] = f2bf(a1[3]);
                    *(bf16x8*)&Bsl[row * 40 + ch * 8] = tv;
                }
            }
        } else {
            // channel-major: wide vector loads along n, scalar LDS scatter.
            const short* Bs = (const short*)Braw;
            int kk = tid & 31, n0 = (tid >> 5) << 4;
            const short* src = Bs + (size_t)(k0 + kk) * BN + bn + n0;
            i32x4 v0 = *(const i32x4*)src;
            i32x4 v1 = *(const i32x4*)(src + 8);
            short tmp[16];
            *(i32x4*)&tmp[0] = v0;
            *(i32x4*)&tmp[8] = v1;
            short* dst = &Bsl[n0 * 40 + kk];
#pragma unroll
            for (int i = 0; i < 16; i++) dst[i * 40] = tmp[i];
        }
        __syncthreads();

        bf16x8 bfrag[4];
#pragma unroll
        for (int ct = 0; ct < 4; ct++)
            bfrag[ct] = *(const bf16x8*)&Bsl[(cw + ct * 16 + m) * 40 + q * 8];
#pragma unroll
        for (int rt = 0; rt < 4; rt++) {
            bf16x8 afrag = *(const bf16x8*)&Asl[(rw + rt * 16 + m) * 40 + q * 8];
#pragma unroll
            for (int ct = 0; ct < 4; ct++)
                acc[rt][ct] = __builtin_amdgcn_mfma_f32_16x16x32_bf16(
                    afrag, bfrag[ct], acc[rt][ct], 0, 0, 0);
        }
        __syncthreads();
    }

    if (MODE == 4) {
        float part[4] = {};
#pragma unroll
        for (int ct = 0; ct < 4; ct++) {
#pragma unroll
            for (int rt = 0; rt < 4; rt++) {
#pragma unroll
                for (int r = 0; r < 4; r++) {
                    int row = rw + rt * 16 + q * 4 + r;
                    part[ct] += fmaxf(acc[rt][ct][r] + bias[row], 0.0f) * w_o2[row];
                }
            }
        }
#pragma unroll
        for (int ct = 0; ct < 4; ct++) {
            part[ct] += __shfl_xor(part[ct], 16);
            part[ct] += __shfl_xor(part[ct], 32);
        }
        float* sred = (float*)Asl;   // [2][128]
        if (q == 0) {
#pragma unroll
            for (int ct = 0; ct < 4; ct++)
                sred[(wave & 1) * 128 + cw + ct * 16 + m] = part[ct];
        }
        __syncthreads();
        if (tid < 128) {
            int g = bn + tid;
            if (g < I_NODES)
                outv[g] = sigmoidf_(sred[tid] + sred[128 + tid] + b_o2[0]);
        }
        return;
    }

#pragma unroll
    for (int rt = 0; rt < 4; rt++) {
#pragma unroll
        for (int ct = 0; ct < 4; ct++) {
            int col = bn + cw + ct * 16 + m;
#pragma unroll
            for (int r = 0; r < 4; r++) {
                int row = bm + rw + rt * 16 + q * 4 + r;
                float v = acc[rt][ct][r] + bias[row];
                if (MODE == 0) {
                    if (ACT == 1) v = fmaxf(v, 0.0f);
                    else if (ACT == 2) v = sigmoidf_(v);
                    fout[(size_t)row * ON + COLOFF + col] = v;
                } else if (MODE == 2) {
                    if (ACT == 1) v = fmaxf(v, 0.0f);
                    else if (ACT == 2) v = sigmoidf_(v);
                    bout[(size_t)row * ON + col] = f2bf(v);
                } else {
                    size_t idx = (size_t)row * NT + col;
                    float t = bf2f(e1[idx]) * bf2f(caf[idx]) + sigmoidf_(v) * bf2f(e2[idx]);
                    bout[idx] = f2bf(t);
                }
            }
        }
    }
}

template <int ACT, int MODE, int BSRC, int BLAYOUT>
__global__ __launch_bounds__(256) void gemm_t(
    const short* A, const void* B, const float* bias,
    float* fout, float* fout1, float* fout2, short* bout,
    const short* caf, const short* e1, const short* e2,
    const float* w_o2, const float* b_o2, float* outv,
    int K, int BN, int ON, int COLOFF)
{
    __shared__ short Asl[128 * 40];
    __shared__ short Bsl[128 * 40];
    gemm_body<ACT, MODE, BSRC, BLAYOUT>(Asl, Bsl, A, B, bias, fout, fout1, fout2,
                                        bout, caf, e1, e2, w_o2, b_o2, outv,
                                        K, BN, ON, COLOFF);
}

// two independent leaf GEMMs in one dispatch (blockIdx.z selects)
__global__ __launch_bounds__(256) void gemm_leafpair(
    const short* wT_btoa, const float* cbl, const float* b_btoa, short* cbT,
    const short* wT_ca,   const short* cafT, const float* b_ca,  short* waT)
{
    __shared__ short Asl[128 * 40];
    __shared__ short Bsl[128 * 40];
    if (blockIdx.z == 0)
        gemm_body<0, 2, 1, 0>(Asl, Bsl, wT_btoa, cbl, b_btoa,
                              nullptr, nullptr, nullptr, cbT,
                              nullptr, nullptr, nullptr, nullptr, nullptr, nullptr,
                              320, 0, NT, 0);
    else
        gemm_body<2, 2, 0, 1>(Asl, Bsl, wT_ca, cafT, b_ca,
                              nullptr, nullptr, nullptr, waT,
                              nullptr, nullptr, nullptr, nullptr, nullptr, nullptr,
                              256, NT, NT, 0);
}

// ---------------------------------------------------------------------------
// xou GEMM: XCD-swizzled 128x128 tiles, 2-phase double-buffered B staging
// (T3/T14-lite), A fragments read DIRECTLY from the L2-resident 384 KB
// weight (no A-LDS). Per step: issue p+1 global loads -> ds_read+MFMA on
// buf[p] -> barrier -> ds_write buf[p^1] -> barrier. Load latency hides
// under the 16 MFMAs.
// Row r: 0-255 xx (raw, bf16), 256-511 ff (sigmoid, fp32), 512-767 rr
// (sigmoid, bf16).
// ---------------------------------------------------------------------------
__global__ __launch_bounds__(256) void gemm_xou(
    const short* __restrict__ A,      // wT_xou [768][256] bf16
    const short* __restrict__ B,      // xT [256][32768] bf16
    const float* __restrict__ bias,   // b_xou [768]
    float* __restrict__ ffT, short* __restrict__ xxT, short* __restrict__ rrT)
{
    __shared__ short Bsl0[128 * 40];
    __shared__ short Bsl1[128 * 40];
    const int tid = threadIdx.x;
    const int L = blockIdx.x;
    const int xcd = L & 7, s = L >> 3;
    const int bm = (s % 6) * 128;
    const int bn = ((s / 6) * 8 + xcd) * 128;

    const int wave = tid >> 6, lane = tid & 63;
    const int m = lane & 15, q = lane >> 4;
    const int rw = (wave & 1) * 64, cw = (wave >> 1) * 64;

    const int kk = tid & 31, n0 = (tid >> 5) << 4;
    const short* bsrc = B + (size_t)kk * NT + bn + n0;

    // prologue: stage k-step 0 into Bsl0
    {
        short tmp[16];
        *(i32x4*)&tmp[0] = *(const i32x4*)bsrc;
        *(i32x4*)&tmp[8] = *(const i32x4*)(bsrc + 8);
        short* dst = &Bsl0[n0 * 40 + kk];
#pragma unroll
        for (int i = 0; i < 16; i++) dst[i * 40] = tmp[i];
    }
    __syncthreads();

    f32x4 acc[4][4] = {};
    short* cur = Bsl0;
    short* nxt = Bsl1;

    for (int p = 0; p < 8; p++) {
        // issue next-step global loads early (latency hides under MFMA)
        short nbuf[16];
        if (p < 7) {
            const short* src = bsrc + (size_t)(p + 1) * 32 * NT;
            *(i32x4*)&nbuf[0] = *(const i32x4*)src;
            *(i32x4*)&nbuf[8] = *(const i32x4*)(src + 8);
        }
        // compute on cur; A-frags direct from global (L2-resident weight)
        bf16x8 bfrag[4];
#pragma unroll
        for (int ct = 0; ct < 4; ct++)
            bfrag[ct] = *(const bf16x8*)&cur[(cw + ct * 16 + m) * 40 + q * 8];
#pragma unroll
        for (int rt = 0; rt < 4; rt++) {
            bf16x8 afrag = *(const bf16x8*)(A + (size_t)(bm + rw + rt * 16 + m) * 256 + p * 32 + q * 8);
#pragma unroll
            for (int ct = 0; ct < 4; ct++)
                acc[rt][ct] = __builtin_amdgcn_mfma_f32_16x16x32_bf16(
                    afrag, bfrag[ct], acc[rt][ct], 0, 0, 0);
        }
        if (p < 7) {
            __syncthreads();      // nxt's last readers (step p-1) are done
            short* dst = &nxt[n0 * 40 + kk];
#pragma unroll
            for (int i = 0; i < 16; i++) dst[i * 40] = nbuf[i];
            __syncthreads();      // nxt visible to all
            short* t2 = cur; cur = nxt; nxt = t2;
        }
    }

#pragma unroll
    for (int rt = 0; rt < 4; rt++) {
#pragma unroll
        for (int ct = 0; ct < 4; ct++) {
            int col = bn + cw + ct * 16 + m;
#pragma unroll
            for (int r = 0; r < 4; r++) {
                int row = bm + rw + rt * 16 + q * 4 + r;
                float v = acc[rt][ct][r] + bias[row];
                int seg = row >> 8, rl = row & 255;
                if (seg == 0)      xxT[(size_t)rl * NT + col] = f2bf(v);
                else if (seg == 1) ffT[(size_t)rl * NT + col] = sigmoidf_(v);
                else               rrT[(size_t)rl * NT + col] = f2bf(sigmoidf_(v));
            }
        }
    }
}

// ---------------------------------------------------------------------------
// levels 1..14, split per (channel, half-tree): 512 blocks x 1024 threads.
// Internal-node c lives entirely in LDS (16383 floats). xx/rr bf16.
// ---------------------------------------------------------------------------
__global__ __launch_bounds__(1024) void levels_T(
    float* __restrict__ cT, const float* __restrict__ ffT,
    const short* __restrict__ xxT, const short* __restrict__ rrT,
    const short* __restrict__ xT, short* __restrict__ hT)
{
    __shared__ float cl[16383];
    const int j = blockIdx.x >> 1;          // channel
    const int s = 1 + (blockIdx.x & 1);     // subtree root (global node 1 or 2)
    float* crow = cT + (size_t)j * CSTRIDE;
    const float* frow = ffT + (size_t)j * NT;
    const short* xrow = xxT + (size_t)j * NT;
    const short* rrow = rrT + (size_t)j * NT;
    const short* xbrow = xT + (size_t)j * NT;
    short* hrow = hT + (size_t)j * NT;

    // bottom internal level (local depth 13): children are global leaves
    {
        const int goff = s << 13;
#pragma unroll 2
        for (int idx = threadIdx.x; idx < 8192; idx += 1024) {
            int l = 8191 + idx;
            int g = goff + l;
            float cs = crow[2 * g + 1] + crow[2 * g + 2];
            float f = frow[g];
            float cv = f * cs + (1.0f - f) * bf2f(xrow[g]);
            cl[l] = cv;
            float r = bf2f(rrow[g]);
            hrow[g] = f2bf(r * tanhf_(cv) + (1.0f - r) * bf2f(xbrow[g]));
        }
    }
    __syncthreads();
    for (int dl = 12; dl >= 0; dl--) {
        int cnt = 1 << dl;
        int goff = s << dl;
        for (int idx = threadIdx.x; idx < cnt; idx += 1024) {
            int l = cnt - 1 + idx;
            int g = goff + l;
            float cs = cl[2 * l + 1] + cl[2 * l + 2];
            float f = frow[g];
            float cv = f * cs + (1.0f - f) * bf2f(xrow[g]);
            cl[l] = cv;
            float r = bf2f(rrow[g]);
            hrow[g] = f2bf(r * tanhf_(cv) + (1.0f - r) * bf2f(xbrow[g]));
            if (dl == 0) crow[g] = cv;      // export c[1]/c[2] for root
        }
        __syncthreads();
    }
}

// root finisher: node 0 for all 256 channels
__global__ __launch_bounds__(256) void levels_root(
    float* __restrict__ cT, const float* __restrict__ ffT,
    const short* __restrict__ xxT, const short* __restrict__ rrT,
    const short* __restrict__ xT, short* __restrict__ hT)
{
    int j = threadIdx.x;
    float cs = cT[(size_t)j * CSTRIDE + 1] + cT[(size_t)j * CSTRIDE + 2];
    float f = ffT[(size_t)j * NT];
    float cv = f * cs + (1.0f - f) * bf2f(xxT[(size_t)j * NT]);
    float r = bf2f(rrT[(size_t)j * NT]);
    hT[(size_t)j * NT] = f2bf(r * tanhf_(cv) + (1.0f - r) * bf2f(xT[(size_t)j * NT]));
}

// ---------------------------------------------------------------------------
extern "C" void kernel_launch(void* const* d_in, const int* in_sizes, int n_in,
                              void* d_out, int out_size, void* d_ws, size_t ws_size,
                              hipStream_t stream)
{
    const float* oper  = (const float*)d_in[0];
    const float* tbf   = (const float*)d_in[1];
    const float* ftf   = (const float*)d_in[2];
    const float* jnf   = (const float*)d_in[3];
    const float* c_a   = (const float*)d_in[4];
    const float* c_b   = (const float*)d_in[5];
    const float* w_op1 = (const float*)d_in[6],  *b_op1 = (const float*)d_in[7];
    const float* w_op2 = (const float*)d_in[8],  *b_op2 = (const float*)d_in[9];
    const float* w_tb1 = (const float*)d_in[10], *b_tb1 = (const float*)d_in[11];
    const float* w_tb2 = (const float*)d_in[12], *b_tb2 = (const float*)d_in[13];
    const float* w_ft1 = (const float*)d_in[14], *b_ft1 = (const float*)d_in[15];
    const float* w_ft2 = (const float*)d_in[16], *b_ft2 = (const float*)d_in[17];
    const float* w_jn1 = (const float*)d_in[18], *b_jn1 = (const float*)d_in[19];
    const float* w_jn2 = (const float*)d_in[20], *b_jn2 = (const float*)d_in[21];
    const float* w_xou = (const float*)d_in[22], *b_xou = (const float*)d_in[23];
    const float* w_ab  = (const float*)d_in[24], *b_ab  = (const float*)d_in[25];
    const float* w_btoa= (const float*)d_in[26], *b_btoa= (const float*)d_in[27];
    const float* w_ca  = (const float*)d_in[28], *b_ca  = (const float*)d_in[29];
    const float* w_cb  = (const float*)d_in[30], *b_cb  = (const float*)d_in[31];
    const float* w_o1  = (const float*)d_in[32], *b_o1  = (const float*)d_in[33];
    const float* w_o2  = (const float*)d_in[34], *b_o2  = (const float*)d_in[35];

    char* WS = (char*)d_ws;
    short* wT_xou  = (short*)WS;                 // 196608
    short* wT_btoa = wT_xou  + 196608;           // 81920
    short* wT_ca   = wT_btoa + 81920;            // 65536
    short* wT_cb   = wT_ca   + 65536;            // 65536
    short* wT_ab   = wT_cb   + 65536;            // 65536
    short* wT_o1   = wT_ab   + 65536;            // 32768
    short* W1T     = wT_o1   + 32768;            // 24576 (256 x 96)
    short* W2T     = W1T     + 24576;            // 65536 (256 x 256)
    float* b1cat   = (float*)(W2T + 65536);      // 256
    float* b2cat   = b1cat + 256;                // 256

    const size_t MB = 1 << 20;
    const size_t OFF_XF   = 2 * MB;                              // 6.3 MB node-major
    const size_t OFF_HE   = OFF_XF  + (size_t)32768 * 96 * 2;    // henc_T 16 MB
    const size_t OFF_X    = OFF_HE  + (size_t)256 * NT * 2;      // x_T 16 MB
    const size_t OFF_XX   = OFF_X   + (size_t)256 * NT * 2;      // xx_T bf16 (region 32 MB)
    const size_t OFF_FF   = OFF_XX  + (size_t)256 * NT * 4;      // ff_T fp32 32 MB
    const size_t OFF_RR   = OFF_FF  + (size_t)256 * NT * 4;      // rr_T bf16 (region 32 MB)
    const size_t OFF_C    = OFF_RR  + (size_t)256 * NT * 4;      // c_T 64 MB
    const size_t OFF_H    = OFF_C   + (size_t)256 * CSTRIDE * 4; // h_T 16 MB
    const size_t OFF_CB   = OFF_H   + (size_t)256 * NT * 2;      // cb_T 16 MB
    const size_t OFF_WA   = OFF_CB  + (size_t)256 * NT * 2;      // wa_T/t_T 16 MB
    const size_t OFF_CAT  = OFF_WA  + (size_t)256 * NT * 2;      // caf_T 16 MB bf16

    short* xfeat = (short*)(WS + OFF_XF);
    short* hencT = (short*)(WS + OFF_HE);
    short* xT    = (short*)(WS + OFF_X);
    short* xxT   = (short*)(WS + OFF_XX);
    float* ffT   = (float*)(WS + OFF_FF);
    short* rrT   = (short*)(WS + OFF_RR);
    float* cT    = (float*)(WS + OFF_C);
    short* hT    = (short*)(WS + OFF_H);
    short* cbT   = (short*)(WS + OFF_CB);
    short* waT   = (short*)(WS + OFF_WA);
    short* cafT  = (short*)(WS + OFF_CAT);
    float* out   = (float*)d_out;
    const float* calf = c_a + (size_t)I_NODES * 256;   // [32768 x 256] fp32
    const float* cbl  = c_b + (size_t)I_NODES * 320;   // [32768 x 320] fp32

    // 1. prep (weights + features + leaf-output constant + caf transpose)
    prep_all<<<PREP_BLOCKS + 2048, 256, 0, stream>>>(
        w_xou, w_btoa, w_ca, w_cb, w_ab, w_o1,
        w_op1, w_tb1, w_ft1, w_jn1, w_op2, w_tb2, w_ft2, w_jn2,
        b_op1, b_tb1, b_ft1, b_jn1, b_op2, b_tb2, b_ft2, b_jn2,
        oper, tbf, ftf, jnf, b_o1, w_o2, b_o2, calf,
        wT_xou, wT_btoa, wT_ca, wT_cb, wT_ab, wT_o1, W1T, W2T, b1cat, b2cat,
        xfeat, out, cafT);

    // 2. encoder: henc_T = relu(W1T @ xfeat) ; x_T = relu(W2T @ henc_T)
    gemm_t<1, 2, 0, 0><<<dim3(2, 256), 256, 0, stream>>>(
        W1T, xfeat, b1cat, nullptr, nullptr, nullptr, hencT,
        nullptr, nullptr, nullptr, nullptr, nullptr, nullptr, 96, 0, NT, 0);
    gemm_t<1, 2, 0, 1><<<dim3(2, 256), 256, 0, stream>>>(
        W2T, hencT, b2cat, nullptr, nullptr, nullptr, xT,
        nullptr, nullptr, nullptr, nullptr, nullptr, nullptr, 256, NT, NT, 0);

    // 3. xou (2-phase dbuf B + direct-A + XCD swizzle)
    gemm_xou<<<1536, 256, 0, stream>>>(wT_xou, xT, b_xou, ffT, xxT, rrT);

    // 4. leaf chain: (cb_T | wa_T) -> t_T (fused wb+t) -> c_T leaf region
    gemm_leafpair<<<dim3(2, 256, 2), 256, 0, stream>>>(
        wT_btoa, cbl, b_btoa, cbT, wT_ca, cafT, b_ca, waT);
    gemm_t<0, 3, 0, 1><<<dim3(2, 256), 256, 0, stream>>>(
        wT_cb, cbT, b_cb, nullptr, nullptr, nullptr, waT /* t in-place */,
        cafT, waT, cbT, nullptr, nullptr, nullptr, 256, NT, NT, 0);
    gemm_t<1, 0, 0, 1><<<dim3(2, 256), 256, 0, stream>>>(
        wT_ab, waT, b_ab, cT, nullptr, nullptr, nullptr,
        nullptr, nullptr, nullptr, nullptr, nullptr, nullptr,
        256, NT, CSTRIDE, I_NODES);

    // 5. levels 1..14 in LDS-resident subtrees, then root
    levels_T<<<512, 1024, 0, stream>>>(cT, ffT, xxT, rrT, xT, hT);
    levels_root<<<1, 256, 0, stream>>>(cT, ffT, xxT, rrT, xT, hT);

    // 6. output head fused with final dot+sigmoid (internal nodes)
    gemm_t<1, 4, 0, 1><<<dim3(1, 256), 256, 0, stream>>>(
        wT_o1, hT, b_o1, nullptr, nullptr, nullptr, nullptr,
        nullptr, nullptr, nullptr, w_o2, b_o2, out, 256, NT, NT, 0);
}

// Round 6
// 425.767 us; speedup vs baseline: 1.0220x; 1.0220x over previous
//
#include <hip/hip_runtime.h>
#include <cstdint>

#define I_NODES 32767
#define N_NODES 65535
#define NLEAF   32768
#define NT      32768          // node columns for channel-major activations
#define CSTRIDE 65536
#define PREP_BLOCKS 4002

typedef float f32x4 __attribute__((ext_vector_type(4)));
typedef short bf16x8 __attribute__((ext_vector_type(8)));
typedef int   i32x4 __attribute__((ext_vector_type(4)));
typedef int   i32x2 __attribute__((ext_vector_type(2)));

__device__ __forceinline__ float sigmoidf_(float v) {
    return 1.0f / (1.0f + __expf(-v));
}
__device__ __forceinline__ float tanhf_(float v) {
    return 1.0f - 2.0f / (1.0f + __expf(2.0f * v));
}
__device__ __forceinline__ short f2bf(float f) {
    union { float f; unsigned u; } v; v.f = f;
    unsigned r = (v.u + 0x7FFF + ((v.u >> 16) & 1)) >> 16;
    return (short)r;
}
__device__ __forceinline__ float bf2f(short b) {
    union { float f; unsigned u; } v; v.u = ((unsigned)(unsigned short)b) << 16;
    return v.f;
}

// ---------------------------------------------------------------------------
// prep_all: weight transposes->bf16 (wT[outch][inch]) + packed encoder
// weights + biases + feature pack (node-major, 8-wide vector stores) +
// leaf-output constant.
// Blocks >= PREP_BLOCKS: LDS-tiled transpose c_a leaves -> cafT bf16.
// ---------------------------------------------------------------------------
__global__ __launch_bounds__(256) void prep_all(
    const float* __restrict__ w_xou, const float* __restrict__ w_btoa,
    const float* __restrict__ w_ca,  const float* __restrict__ w_cb,
    const float* __restrict__ w_ab,  const float* __restrict__ w_o1,
    const float* __restrict__ w_op1, const float* __restrict__ w_tb1,
    const float* __restrict__ w_ft1, const float* __restrict__ w_jn1,
    const float* __restrict__ w_op2, const float* __restrict__ w_tb2,
    const float* __restrict__ w_ft2, const float* __restrict__ w_jn2,
    const float* __restrict__ b_op1, const float* __restrict__ b_tb1,
    const float* __restrict__ b_ft1, const float* __restrict__ b_jn1,
    const float* __restrict__ b_op2, const float* __restrict__ b_tb2,
    const float* __restrict__ b_ft2, const float* __restrict__ b_jn2,
    const float* __restrict__ oper,  const float* __restrict__ tbf,
    const float* __restrict__ ftf,   const float* __restrict__ jnf,
    const float* __restrict__ b_o1,  const float* __restrict__ w_o2,
    const float* __restrict__ b_o2,  const float* __restrict__ caf,
    short* __restrict__ wT_xou, short* __restrict__ wT_btoa,
    short* __restrict__ wT_ca,  short* __restrict__ wT_cb,
    short* __restrict__ wT_ab,  short* __restrict__ wT_o1,
    short* __restrict__ W1T,    short* __restrict__ W2T,
    float* __restrict__ b1cat,  float* __restrict__ b2cat,
    short* __restrict__ xfeat,  float* __restrict__ outv,
    short* __restrict__ cafT)
{
    if (blockIdx.x >= PREP_BLOCKS) {
        // transpose section: [32768 x 256] f32 -> [256 x 32768] bf16
        __shared__ float tile[64][65];
        const int bid = blockIdx.x - PREP_BLOCKS;
        const int t = threadIdx.x;
        const int r0 = (bid & 511) * 64;   // leaf rows
        const int c0 = (bid >> 9) * 64;    // channels
        const int lane = t & 63, seg = t >> 6;
#pragma unroll
        for (int i = 0; i < 16; i++) {
            int rr = seg + i * 4;
            tile[rr][lane] = caf[(size_t)(r0 + rr) * 256 + c0 + lane];
        }
        __syncthreads();
#pragma unroll
        for (int i = 0; i < 16; i++) {
            int cc = seg + i * 4;
            cafT[(size_t)(c0 + cc) * NT + r0 + lane] = f2bf(tile[lane][cc]);
        }
        return;
    }
    int r = blockIdx.x * 256 + threadIdx.x;
    if (r < 196608) { wT_xou[r] = f2bf(w_xou[(size_t)(r % 256) * 768 + r / 256]); return; }
    r -= 196608;
    if (r < 81920)  { wT_btoa[r] = f2bf(w_btoa[(size_t)(r % 320) * 256 + r / 320]); return; }
    r -= 81920;
    if (r < 65536)  { wT_ca[r] = f2bf(w_ca[(size_t)(r % 256) * 256 + r / 256]); return; }
    r -= 65536;
    if (r < 65536)  { wT_cb[r] = f2bf(w_cb[(size_t)(r % 256) * 256 + r / 256]); return; }
    r -= 65536;
    if (r < 65536)  { wT_ab[r] = f2bf(w_ab[(size_t)(r % 256) * 256 + r / 256]); return; }
    r -= 65536;
    if (r < 32768)  { wT_o1[r] = f2bf(w_o1[(size_t)(r % 256) * 128 + r / 256]); return; }
    r -= 32768;
    if (r < 24576) {
        int j = r / 96, k = r % 96;
        int s = j >> 6, jj = j & 63;
        int off = (s == 0) ? 0 : (s == 1) ? 4 : (s == 2) ? 15 : 33;
        int Ks  = (s == 0) ? 4 : (s == 1) ? 11 : (s == 2) ? 18 : 37;
        const float* w = (s == 0) ? w_op1 : (s == 1) ? w_tb1 : (s == 2) ? w_ft1 : w_jn1;
        W1T[r] = (k >= off && k < off + Ks) ? f2bf(w[(k - off) * 64 + jj]) : (short)0;
        return;
    }
    r -= 24576;
    if (r < 65536) {
        int j = r >> 8, k = r & 255;
        int s = j >> 6, jj = j & 63;
        const float* w = (s == 0) ? w_op2 : (s == 1) ? w_tb2 : (s == 2) ? w_ft2 : w_jn2;
        W2T[r] = ((k >> 6) == s) ? f2bf(w[(k & 63) * 64 + jj]) : (short)0;
        return;
    }
    r -= 65536;
    if (r < 256) {
        int s = r >> 6, jj = r & 63;
        b1cat[r] = (s == 0) ? b_op1[jj] : (s == 1) ? b_tb1[jj] : (s == 2) ? b_ft1[jj] : b_jn1[jj];
        return;
    }
    r -= 256;
    if (r < 256) {
        int s = r >> 6, jj = r & 63;
        b2cat[r] = (s == 0) ? b_op2[jj] : (s == 1) ? b_tb2[jj] : (s == 2) ? b_ft2[jj] : b_jn2[jj];
        return;
    }
    r -= 256;
    if (r < 393216) {
        // xfeat pack, 8 features per thread, one short8 store (G13)
        int node = r / 12, fb = (r % 12) * 8;
        short v8[8];
        if (node < I_NODES) {
#pragma unroll
            for (int i = 0; i < 8; i++) {
                int f = fb + i;
                float v = 0.0f;
                if (f < 4)       v = oper[node * 4 + f];
                else if (f < 15) v = tbf[node * 11 + (f - 4)];
                else if (f < 33) v = ftf[node * 18 + (f - 15)];
                else if (f < 70) v = jnf[node * 37 + (f - 33)];
                v8[i] = f2bf(v);
            }
        } else {
#pragma unroll
            for (int i = 0; i < 8; i++) v8[i] = 0;
        }
        *(bf16x8*)&xfeat[node * 96 + fb] = *(bf16x8*)v8;
        return;
    }
    r -= 393216;
    if (r < 32768) {
        // leaf output: h=0 -> hid = relu(b_o1), out = sigmoid(b_o2 + hid.w_o2)
        float s = 0.0f;
        for (int k = 0; k < 128; k++) s += fmaxf(b_o1[k], 0.0f) * w_o2[k];
        outv[I_NODES + r] = sigmoidf_(s + b_o2[0]);
    }
}

// ---------------------------------------------------------------------------
// Transposed-world MFMA GEMM: out_T[ch][node] = act( A_w[M x K] @ B + bias ).
// A_w = transposed weight, bf16 row-major [M][K]. bm/bn passed by wrapper
// (XCD-swizzled so all m-tiles of an n-tile share an XCD L2).
// BLAYOUT 0: B node-major [32768 x K] (BSRC 0 bf16 / 1 fp32-convert).
// BLAYOUT 1: B channel-major bf16 [K x BN] (BSRC must be 0).
// MODE 0: fp32 fout[row*ON + COLOFF + col] with ACT.
// MODE 2: bf16 bout[row*ON + col] with ACT.
// MODE 3: t-fusion: bout = e1*caf + sigmoid(v)*e2 (all channel-major bf16).
// MODE 4: head fusion (M=128): out[col] = sigmoid(b_o2 + sum_row relu(v)*w_o2[row]).
// ---------------------------------------------------------------------------
template <int ACT, int MODE, int BSRC, int BLAYOUT>
__device__ __forceinline__ void gemm_body(
    short* Asl, short* Bsl, int bm, int bn,
    const short* __restrict__ A, const void* __restrict__ Braw,
    const float* __restrict__ bias,
    float* __restrict__ fout, float* __restrict__ fout1, float* __restrict__ fout2,
    short* __restrict__ bout,
    const short* __restrict__ caf, const short* __restrict__ e1,
    const short* __restrict__ e2,
    const float* __restrict__ w_o2, const float* __restrict__ b_o2,
    float* __restrict__ outv,
    int K, int BN, int ON, int COLOFF)
{
    const int tid = threadIdx.x;
    const int wave = tid >> 6, lane = tid & 63;
    const int m = lane & 15, q = lane >> 4;
    const int rw = (wave & 1) * 64, cw = (wave >> 1) * 64;

    f32x4 acc[4][4] = {};

    for (int k0 = 0; k0 < K; k0 += 32) {
        // A staging: [128 rows][32 k] from bf16 row-major
#pragma unroll
        for (int i = 0; i < 2; i++) {
            int id = tid + i * 256;
            int row = id >> 2, ch = id & 3;
            i32x4 va = *(const i32x4*)(A + (size_t)(bm + row) * K + k0 + ch * 8);
            *(i32x4*)&Asl[row * 40 + ch * 8] = va;
        }
        // B staging -> Bsl[n][k] (pitch 40)
        if (BLAYOUT == 0) {
#pragma unroll
            for (int i = 0; i < 2; i++) {
                int id = tid + i * 256;
                int row = id >> 2, ch = id & 3;
                if (BSRC == 0) {
                    const short* Bs = (const short*)Braw;
                    i32x4 vb = *(const i32x4*)(Bs + (size_t)(bn + row) * K + k0 + ch * 8);
                    *(i32x4*)&Bsl[row * 40 + ch * 8] = vb;
                } else {
                    const float* Bf = (const float*)Braw;
                    const float* src = Bf + (size_t)(bn + row) * K + k0 + ch * 8;
                    f32x4 a0 = *(const f32x4*)src;
                    f32x4 a1 = *(const f32x4*)(src + 4);
                    bf16x8 tv;
                    tv[0] = f2bf(a0[0]); tv[1] = f2bf(a0[1]); tv[2] = f2bf(a0[2]); tv[3] = f2bf(a0[3]);
                    tv[4] = f2bf(a1[0]); tv[5] = f2bf(a1[1]); tv[6] = f2bf(a1[2]); tv[7] = f2bf(a1[3]);
                    *(bf16x8*)&Bsl[row * 40 + ch * 8] = tv;
                }
            }
        } else {
            // channel-major: wide vector loads along n, scalar LDS scatter.
            const short* Bs = (const short*)Braw;
            int kk = tid & 31, n0 = (tid >> 5) << 4;
            const short* src = Bs + (size_t)(k0 + kk) * BN + bn + n0;
            i32x4 v0 = *(const i32x4*)src;
            i32x4 v1 = *(const i32x4*)(src + 8);
            short tmp[16];
            *(i32x4*)&tmp[0] = v0;
            *(i32x4*)&tmp[8] = v1;
            short* dst = &Bsl[n0 * 40 + kk];
#pragma unroll
            for (int i = 0; i < 16; i++) dst[i * 40] = tmp[i];
        }
        __syncthreads();

        bf16x8 bfrag[4];
#pragma unroll
        for (int ct = 0; ct < 4; ct++)
            bfrag[ct] = *(const bf16x8*)&Bsl[(cw + ct * 16 + m) * 40 + q * 8];
#pragma unroll
        for (int rt = 0; rt < 4; rt++) {
            bf16x8 afrag = *(const bf16x8*)&Asl[(rw + rt * 16 + m) * 40 + q * 8];
#pragma unroll
            for (int ct = 0; ct < 4; ct++)
                acc[rt][ct] = __builtin_amdgcn_mfma_f32_16x16x32_bf16(
                    afrag, bfrag[ct], acc[rt][ct], 0, 0, 0);
        }
        __syncthreads();
    }

    if (MODE == 4) {
        float part[4] = {};
#pragma unroll
        for (int ct = 0; ct < 4; ct++) {
#pragma unroll
            for (int rt = 0; rt < 4; rt++) {
#pragma unroll
                for (int r = 0; r < 4; r++) {
                    int row = rw + rt * 16 + q * 4 + r;
                    part[ct] += fmaxf(acc[rt][ct][r] + bias[row], 0.0f) * w_o2[row];
                }
            }
        }
#pragma unroll
        for (int ct = 0; ct < 4; ct++) {
            part[ct] += __shfl_xor(part[ct], 16);
            part[ct] += __shfl_xor(part[ct], 32);
        }
        float* sred = (float*)Asl;   // [2][128]
        if (q == 0) {
#pragma unroll
            for (int ct = 0; ct < 4; ct++)
                sred[(wave & 1) * 128 + cw + ct * 16 + m] = part[ct];
        }
        __syncthreads();
        if (tid < 128) {
            int g = bn + tid;
            if (g < I_NODES)
                outv[g] = sigmoidf_(sred[tid] + sred[128 + tid] + b_o2[0]);
        }
        return;
    }

#pragma unroll
    for (int rt = 0; rt < 4; rt++) {
#pragma unroll
        for (int ct = 0; ct < 4; ct++) {
            int col = bn + cw + ct * 16 + m;
#pragma unroll
            for (int r = 0; r < 4; r++) {
                int row = bm + rw + rt * 16 + q * 4 + r;
                float v = acc[rt][ct][r] + bias[row];
                if (MODE == 0) {
                    if (ACT == 1) v = fmaxf(v, 0.0f);
                    else if (ACT == 2) v = sigmoidf_(v);
                    fout[(size_t)row * ON + COLOFF + col] = v;
                } else if (MODE == 2) {
                    if (ACT == 1) v = fmaxf(v, 0.0f);
                    else if (ACT == 2) v = sigmoidf_(v);
                    bout[(size_t)row * ON + col] = f2bf(v);
                } else {
                    size_t idx = (size_t)row * NT + col;
                    float t = bf2f(e1[idx]) * bf2f(caf[idx]) + sigmoidf_(v) * bf2f(e2[idx]);
                    bout[idx] = f2bf(t);
                }
            }
        }
    }
}

// MT m-tiles per n-tile, XCD-swizzled so they share an XCD L2 (grid MT*256).
template <int ACT, int MODE, int BSRC, int BLAYOUT>
__global__ __launch_bounds__(256) void gemm_t(
    const short* A, const void* B, const float* bias,
    float* fout, float* fout1, float* fout2, short* bout,
    const short* caf, const short* e1, const short* e2,
    const float* w_o2, const float* b_o2, float* outv,
    int K, int BN, int ON, int COLOFF, int MT)
{
    __shared__ short Asl[128 * 40];
    __shared__ short Bsl[128 * 40];
    int L = blockIdx.x, bm, bn;
    if (MT == 1) { bm = 0; bn = L * 128; }
    else {
        int xcd = L & 7, s = L >> 3;
        bm = (s % MT) * 128;
        bn = ((s / MT) * 8 + xcd) * 128;
    }
    gemm_body<ACT, MODE, BSRC, BLAYOUT>(Asl, Bsl, bm, bn, A, B, bias,
                                        fout, fout1, fout2,
                                        bout, caf, e1, e2, w_o2, b_o2, outv,
                                        K, BN, ON, COLOFF);
}

// two independent leaf GEMMs in one dispatch, 1024 blocks 1-D, XCD-swizzled
__global__ __launch_bounds__(256) void gemm_leafpair(
    const short* wT_btoa, const float* cbl, const float* b_btoa, short* cbT,
    const short* wT_ca,   const short* cafT, const float* b_ca,  short* waT)
{
    __shared__ short Asl[128 * 40];
    __shared__ short Bsl[128 * 40];
    int L = blockIdx.x;
    int xcd = L & 7, s = L >> 3;
    int mi = s & 1, u = s >> 1;
    int pair = u * 8 + xcd;              // 0..511
    int bm = mi * 128, bn = (pair & 255) * 128, z = pair >> 8;
    if (z == 0)
        gemm_body<0, 2, 1, 0>(Asl, Bsl, bm, bn, wT_btoa, cbl, b_btoa,
                              nullptr, nullptr, nullptr, cbT,
                              nullptr, nullptr, nullptr, nullptr, nullptr, nullptr,
                              320, 0, NT, 0);
    else
        gemm_body<2, 2, 0, 1>(Asl, Bsl, bm, bn, wT_ca, cafT, b_ca,
                              nullptr, nullptr, nullptr, waT,
                              nullptr, nullptr, nullptr, nullptr, nullptr, nullptr,
                              256, NT, NT, 0);
}

// ---------------------------------------------------------------------------
// xou GEMM: round-4 winner. 128x128 tiles, A+B LDS-staged per k-step,
// XCD-aware 1-D swizzle (1536 blocks: all 6 m-tiles of an n-tile on one XCD).
// Row r: 0-255 xx (raw, bf16), 256-511 ff (sigmoid, fp32), 512-767 rr
// (sigmoid, bf16).
// ---------------------------------------------------------------------------
__global__ __launch_bounds__(256) void gemm_xou(
    const short* __restrict__ A,      // wT_xou [768][256] bf16
    const short* __restrict__ B,      // xT [256][32768] bf16
    const float* __restrict__ bias,   // b_xou [768]
    float* __restrict__ ffT, short* __restrict__ xxT, short* __restrict__ rrT)
{
    __shared__ short Asl[128 * 40];
    __shared__ short Bsl[128 * 40];
    const int tid = threadIdx.x;
    const int L = blockIdx.x;
    const int xcd = L & 7, s = L >> 3;
    const int bm = (s % 6) * 128;
    const int bn = ((s / 6) * 8 + xcd) * 128;

    const int wave = tid >> 6, lane = tid & 63;
    const int m = lane & 15, q = lane >> 4;
    const int rw = (wave & 1) * 64, cw = (wave >> 1) * 64;

    f32x4 acc[4][4] = {};

    for (int k0 = 0; k0 < 256; k0 += 32) {
        // A staging: [128 rows][32 k] from bf16 row-major
#pragma unroll
        for (int i = 0; i < 2; i++) {
            int id = tid + i * 256;
            int row = id >> 2, ch = id & 3;
            i32x4 va = *(const i32x4*)(A + (size_t)(bm + row) * 256 + k0 + ch * 8);
            *(i32x4*)&Asl[row * 40 + ch * 8] = va;
        }
        // B staging: channel-major, wide vector loads along n, scatter
        {
            int kk = tid & 31, n0 = (tid >> 5) << 4;
            const short* src = B + (size_t)(k0 + kk) * NT + bn + n0;
            i32x4 v0 = *(const i32x4*)src;
            i32x4 v1 = *(const i32x4*)(src + 8);
            short tmp[16];
            *(i32x4*)&tmp[0] = v0;
            *(i32x4*)&tmp[8] = v1;
            short* dst = &Bsl[n0 * 40 + kk];
#pragma unroll
            for (int i = 0; i < 16; i++) dst[i * 40] = tmp[i];
        }
        __syncthreads();

        bf16x8 bfrag[4];
#pragma unroll
        for (int ct = 0; ct < 4; ct++)
            bfrag[ct] = *(const bf16x8*)&Bsl[(cw + ct * 16 + m) * 40 + q * 8];
#pragma unroll
        for (int rt = 0; rt < 4; rt++) {
            bf16x8 afrag = *(const bf16x8*)&Asl[(rw + rt * 16 + m) * 40 + q * 8];
#pragma unroll
            for (int ct = 0; ct < 4; ct++)
                acc[rt][ct] = __builtin_amdgcn_mfma_f32_16x16x32_bf16(
                    afrag, bfrag[ct], acc[rt][ct], 0, 0, 0);
        }
        __syncthreads();
    }

#pragma unroll
    for (int rt = 0; rt < 4; rt++) {
#pragma unroll
        for (int ct = 0; ct < 4; ct++) {
            int col = bn + cw + ct * 16 + m;
#pragma unroll
            for (int r = 0; r < 4; r++) {
                int row = bm + rw + rt * 16 + q * 4 + r;
                float v = acc[rt][ct][r] + bias[row];
                int seg = row >> 8, rl = row & 255;
                if (seg == 0)      xxT[(size_t)rl * NT + col] = f2bf(v);
                else if (seg == 1) ffT[(size_t)rl * NT + col] = sigmoidf_(v);
                else               rrT[(size_t)rl * NT + col] = f2bf(sigmoidf_(v));
            }
        }
    }
}

// ---------------------------------------------------------------------------
// levels 1..14, split per (channel, half-tree): 512 blocks x 1024 threads.
// Internal-node c lives entirely in LDS (16383 floats). Leaf c is bf16
// (clT). Subtree-root c exported to cexp[ch][2] for the root finisher.
// ---------------------------------------------------------------------------
__global__ __launch_bounds__(1024) void levels_T(
    const short* __restrict__ clT, const float* __restrict__ ffT,
    const short* __restrict__ xxT, const short* __restrict__ rrT,
    const short* __restrict__ xT, short* __restrict__ hT,
    float* __restrict__ cexp)
{
    __shared__ float cl[16383];
    const int j = blockIdx.x >> 1;          // channel
    const int s = 1 + (blockIdx.x & 1);     // subtree root (global node 1 or 2)
    const short* clrow = clT + (size_t)j * NT;
    const float* frow = ffT + (size_t)j * NT;
    const short* xrow = xxT + (size_t)j * NT;
    const short* rrow = rrT + (size_t)j * NT;
    const short* xbrow = xT + (size_t)j * NT;
    short* hrow = hT + (size_t)j * NT;

    // bottom internal level (local depth 13): children are global leaves
    {
        const int goff = s << 13;
#pragma unroll 2
        for (int idx = threadIdx.x; idx < 8192; idx += 1024) {
            int l = 8191 + idx;
            int g = goff + l;
            float cs = bf2f(clrow[2 * g + 1 - I_NODES]) + bf2f(clrow[2 * g + 2 - I_NODES]);
            float f = frow[g];
            float cv = f * cs + (1.0f - f) * bf2f(xrow[g]);
            cl[l] = cv;
            float r = bf2f(rrow[g]);
            hrow[g] = f2bf(r * tanhf_(cv) + (1.0f - r) * bf2f(xbrow[g]));
        }
    }
    __syncthreads();
    for (int dl = 12; dl >= 0; dl--) {
        int cnt = 1 << dl;
        int goff = s << dl;
        for (int idx = threadIdx.x; idx < cnt; idx += 1024) {
            int l = cnt - 1 + idx;
            int g = goff + l;
            float cs = cl[2 * l + 1] + cl[2 * l + 2];
            float f = frow[g];
            float cv = f * cs + (1.0f - f) * bf2f(xrow[g]);
            cl[l] = cv;
            float r = bf2f(rrow[g]);
            hrow[g] = f2bf(r * tanhf_(cv) + (1.0f - r) * bf2f(xbrow[g]));
            if (dl == 0) cexp[j * 2 + (s - 1)] = cv;   // export c[1]/c[2]
        }
        __syncthreads();
    }
}

// root finisher: node 0 for all 256 channels
__global__ __launch_bounds__(256) void levels_root(
    const float* __restrict__ cexp, const float* __restrict__ ffT,
    const short* __restrict__ xxT, const short* __restrict__ rrT,
    const short* __restrict__ xT, short* __restrict__ hT)
{
    int j = threadIdx.x;
    float cs = cexp[j * 2] + cexp[j * 2 + 1];
    float f = ffT[(size_t)j * NT];
    float cv = f * cs + (1.0f - f) * bf2f(xxT[(size_t)j * NT]);
    float r = bf2f(rrT[(size_t)j * NT]);
    hT[(size_t)j * NT] = f2bf(r * tanhf_(cv) + (1.0f - r) * bf2f(xT[(size_t)j * NT]));
}

// ---------------------------------------------------------------------------
extern "C" void kernel_launch(void* const* d_in, const int* in_sizes, int n_in,
                              void* d_out, int out_size, void* d_ws, size_t ws_size,
                              hipStream_t stream)
{
    const float* oper  = (const float*)d_in[0];
    const float* tbf   = (const float*)d_in[1];
    const float* ftf   = (const float*)d_in[2];
    const float* jnf   = (const float*)d_in[3];
    const float* c_a   = (const float*)d_in[4];
    const float* c_b   = (const float*)d_in[5];
    const float* w_op1 = (const float*)d_in[6],  *b_op1 = (const float*)d_in[7];
    const float* w_op2 = (const float*)d_in[8],  *b_op2 = (const float*)d_in[9];
    const float* w_tb1 = (const float*)d_in[10], *b_tb1 = (const float*)d_in[11];
    const float* w_tb2 = (const float*)d_in[12], *b_tb2 = (const float*)d_in[13];
    const float* w_ft1 = (const float*)d_in[14], *b_ft1 = (const float*)d_in[15];
    const float* w_ft2 = (const float*)d_in[16], *b_ft2 = (const float*)d_in[17];
    const float* w_jn1 = (const float*)d_in[18], *b_jn1 = (const float*)d_in[19];
    const float* w_jn2 = (const float*)d_in[20], *b_jn2 = (const float*)d_in[21];
    const float* w_xou = (const float*)d_in[22], *b_xou = (const float*)d_in[23];
    const float* w_ab  = (const float*)d_in[24], *b_ab  = (const float*)d_in[25];
    const float* w_btoa= (const float*)d_in[26], *b_btoa= (const float*)d_in[27];
    const float* w_ca  = (const float*)d_in[28], *b_ca  = (const float*)d_in[29];
    const float* w_cb  = (const float*)d_in[30], *b_cb  = (const float*)d_in[31];
    const float* w_o1  = (const float*)d_in[32], *b_o1  = (const float*)d_in[33];
    const float* w_o2  = (const float*)d_in[34], *b_o2  = (const float*)d_in[35];

    char* WS = (char*)d_ws;
    short* wT_xou  = (short*)WS;                 // 196608
    short* wT_btoa = wT_xou  + 196608;           // 81920
    short* wT_ca   = wT_btoa + 81920;            // 65536
    short* wT_cb   = wT_ca   + 65536;            // 65536
    short* wT_ab   = wT_cb   + 65536;            // 65536
    short* wT_o1   = wT_ab   + 65536;            // 32768
    short* W1T     = wT_o1   + 32768;            // 24576 (256 x 96)
    short* W2T     = W1T     + 24576;            // 65536 (256 x 256)
    float* b1cat   = (float*)(W2T + 65536);      // 256
    float* b2cat   = b1cat + 256;                // 256
    float* cexp    = b2cat + 256;                // 512 (c[1],c[2] per channel)

    const size_t MB = 1 << 20;
    const size_t OFF_XF   = 2 * MB;                              // 6.3 MB node-major
    const size_t OFF_HE   = OFF_XF  + (size_t)32768 * 96 * 2;    // henc_T 16 MB
    const size_t OFF_X    = OFF_HE  + (size_t)256 * NT * 2;      // x_T 16 MB
    const size_t OFF_XX   = OFF_X   + (size_t)256 * NT * 2;      // xx_T bf16 (region 32 MB)
    const size_t OFF_FF   = OFF_XX  + (size_t)256 * NT * 4;      // ff_T fp32 32 MB
    const size_t OFF_RR   = OFF_FF  + (size_t)256 * NT * 4;      // rr_T bf16 (region 32 MB)
    const size_t OFF_C    = OFF_RR  + (size_t)256 * NT * 4;      // cl_T bf16 16 MB (region 64 MB)
    const size_t OFF_H    = OFF_C   + (size_t)256 * CSTRIDE * 4; // h_T 16 MB
    const size_t OFF_CB   = OFF_H   + (size_t)256 * NT * 2;      // cb_T 16 MB
    const size_t OFF_WA   = OFF_CB  + (size_t)256 * NT * 2;      // wa_T/t_T 16 MB
    const size_t OFF_CAT  = OFF_WA  + (size_t)256 * NT * 2;      // caf_T 16 MB bf16

    short* xfeat = (short*)(WS + OFF_XF);
    short* hencT = (short*)(WS + OFF_HE);
    short* xT    = (short*)(WS + OFF_X);
    short* xxT   = (short*)(WS + OFF_XX);
    float* ffT   = (float*)(WS + OFF_FF);
    short* rrT   = (short*)(WS + OFF_RR);
    short* clT   = (short*)(WS + OFF_C);
    short* hT    = (short*)(WS + OFF_H);
    short* cbT   = (short*)(WS + OFF_CB);
    short* waT   = (short*)(WS + OFF_WA);
    short* cafT  = (short*)(WS + OFF_CAT);
    float* out   = (float*)d_out;
    const float* calf = c_a + (size_t)I_NODES * 256;   // [32768 x 256] fp32
    const float* cbl  = c_b + (size_t)I_NODES * 320;   // [32768 x 320] fp32

    // 1. prep (weights + features + leaf-output constant + caf transpose)
    prep_all<<<PREP_BLOCKS + 2048, 256, 0, stream>>>(
        w_xou, w_btoa, w_ca, w_cb, w_ab, w_o1,
        w_op1, w_tb1, w_ft1, w_jn1, w_op2, w_tb2, w_ft2, w_jn2,
        b_op1, b_tb1, b_ft1, b_jn1, b_op2, b_tb2, b_ft2, b_jn2,
        oper, tbf, ftf, jnf, b_o1, w_o2, b_o2, calf,
        wT_xou, wT_btoa, wT_ca, wT_cb, wT_ab, wT_o1, W1T, W2T, b1cat, b2cat,
        xfeat, out, cafT);

    // 2. encoder: henc_T = relu(W1T @ xfeat) ; x_T = relu(W2T @ henc_T)
    gemm_t<1, 2, 0, 0><<<512, 256, 0, stream>>>(
        W1T, xfeat, b1cat, nullptr, nullptr, nullptr, hencT,
        nullptr, nullptr, nullptr, nullptr, nullptr, nullptr, 96, 0, NT, 0, 2);
    gemm_t<1, 2, 0, 1><<<512, 256, 0, stream>>>(
        W2T, hencT, b2cat, nullptr, nullptr, nullptr, xT,
        nullptr, nullptr, nullptr, nullptr, nullptr, nullptr, 256, NT, NT, 0, 2);

    // 3. xou (round-4 winner: staged tiles + bf16 xx/rr + XCD swizzle)
    gemm_xou<<<1536, 256, 0, stream>>>(wT_xou, xT, b_xou, ffT, xxT, rrT);

    // 4. leaf chain: (cb_T | wa_T) -> t_T (fused wb+t) -> cl_T (bf16 leaf c)
    gemm_leafpair<<<1024, 256, 0, stream>>>(
        wT_btoa, cbl, b_btoa, cbT, wT_ca, cafT, b_ca, waT);
    gemm_t<0, 3, 0, 1><<<512, 256, 0, stream>>>(
        wT_cb, cbT, b_cb, nullptr, nullptr, nullptr, waT /* t in-place */,
        cafT, waT, cbT, nullptr, nullptr, nullptr, 256, NT, NT, 0, 2);
    gemm_t<1, 2, 0, 1><<<512, 256, 0, stream>>>(
        wT_ab, waT, b_ab, nullptr, nullptr, nullptr, clT,
        nullptr, nullptr, nullptr, nullptr, nullptr, nullptr, 256, NT, NT, 0, 2);

    // 5. levels 1..14 in LDS-resident subtrees, then root
    levels_T<<<512, 1024, 0, stream>>>(clT, ffT, xxT, rrT, xT, hT, cexp);
    levels_root<<<1, 256, 0, stream>>>(cexp, ffT, xxT, rrT, xT, hT);

    // 6. output head fused with final dot+sigmoid (internal nodes)
    gemm_t<1, 4, 0, 1><<<256, 256, 0, stream>>>(
        wT_o1, hT, b_o1, nullptr, nullptr, nullptr, nullptr,
        nullptr, nullptr, nullptr, w_o2, b_o2, out, 256, NT, NT, 0, 1);
}